// Round 8
// baseline (3252.626 us; speedup 1.0000x reference)
//
#include <hip/hip_runtime.h>
#include <math.h>

// ---------------------------------------------------------------------------
// HAT block — fp32 residual + f16 mirror (X16), f16 activations, MFMA
// everywhere. Weights pre-packed lane-contiguous; B-frags global->VGPR.
// Conv: 2-row halo tiles. GEMM: single-stage 192-wide K super-chunks.
// ---------------------------------------------------------------------------

#define DEV __device__ __forceinline__

constexpr int HH   = 192;
constexpr int WW   = 192;
constexpr int NT   = HH * WW;     // 36864
constexpr int C    = 180;
constexpr int HEADS= 6;
constexpr int HD   = 30;
constexpr int WS   = 16;
constexpr int NWW  = WW / WS;     // 12
constexpr int NWIN = 144;
constexpr int NTW  = 256;
constexpr int OWS  = 24;
constexpr int NKV  = OWS*OWS;     // 576
constexpr int CCH  = 60;
constexpr int CSE  = 6;
constexpr int HID  = 360;
constexpr int DEPTH= 6;

typedef _Float16 h8   __attribute__((ext_vector_type(8)));
typedef _Float16 h4   __attribute__((ext_vector_type(4)));
typedef float    f32x4 __attribute__((ext_vector_type(4)));

constexpr int PKG = 2048;            // gemm pack unit: [nb4][lane64][j8]
constexpr int PKC = 18432;           // conv pack unit: [tap9][nb4][lane64][j8]

constexpr int QKV_PL = 9*6*PKG;
constexpr int PROJ_PL= 3*6*PKG;
constexpr int M1_PL  = 6*6*PKG;
constexpr int M2_PL  = 3*12*PKG;
constexpr int OQ_PL  = 3*6*PKG;
constexpr int OKV_PL = 6*6*PKG;
constexpr int OP_PL  = 3*6*PKG;
constexpr int CC_PL  = 1*6*PKC;
constexpr int CE_PL  = 3*2*PKC;
constexpr int FIN_PL = 3*6*PKC;

constexpr size_t PO_QKV = 0;
constexpr size_t PO_PROJ= PO_QKV + 6ull*QKV_PL;
constexpr size_t PO_M1  = PO_PROJ+ 6ull*PROJ_PL;
constexpr size_t PO_M2  = PO_M1  + 6ull*M1_PL;
constexpr size_t PO_OQ  = PO_M2  + 6ull*M2_PL;
constexpr size_t PO_OKV = PO_OQ  + OQ_PL;
constexpr size_t PO_OP  = PO_OKV + OKV_PL;
constexpr size_t PO_CC  = PO_OP  + OP_PL;
constexpr size_t PO_CE  = PO_CC  + 6ull*CC_PL;
constexpr size_t PO_FIN = PO_CE  + 6ull*CE_PL;
constexpr size_t PK_HALFS = PO_FIN + FIN_PL;

// workspace offsets (floats)
constexpr size_t OFF_X    = 0;                          // X fp32 NT*180
constexpr size_t OFF_A    = OFF_X    + (size_t)NT*C;    // A f16 stride 192
constexpr size_t OFF_B    = OFF_A    + (size_t)NT*C;    // Bq f16 stride 192
constexpr size_t OFF_COMP = OFF_B    + (size_t)NT*C;    // COMP f16 stride 64
constexpr size_t OFF_S    = OFF_COMP + (size_t)NT*CCH;
constexpr size_t OFF_G    = OFF_S    + 64;
constexpr size_t OFF_QKV  = OFF_G    + 64;              // QKV/KV/GELU f16
constexpr size_t OFF_PK   = OFF_QKV  + 16000000;
constexpr size_t OFF_PB   = OFF_PK   + PK_HALFS/2 + 8;
constexpr size_t OFF_X16  = OFF_PB   + 4096;            // X16 f16 stride 192

DEV int win_to_nat(int r, int shift) {
  int w   = r >> 8;
  int pos = r & 255;
  int wh = w / NWW, ww = w - wh*NWW;
  int rh = wh*WS + (pos >> 4);
  int rw = ww*WS + (pos & 15);
  int sh = rh + shift; if (sh >= HH) sh -= HH;
  int sw = rw + shift; if (sw >= WW) sw -= WW;
  return sh*WW + sw;
}

DEV int ocab_src_row(int gr) {
  int w = gr / NKV;
  int t = gr - w*NKV;
  int wh = w / NWW, ww = w - wh*NWW;
  int i = t / OWS, j = t - i*OWS;
  int gh = wh*WS - 4 + i;
  int gw = ww*WS - 4 + j;
  if ((unsigned)gh >= (unsigned)HH || (unsigned)gw >= (unsigned)WW) return -1;
  return (((gh >> 4)*NWW + (gw >> 4)) << 8) + ((gh & 15) << 4) + (gw & 15);
}

DEV float gelu_exact(float v) {
  return 0.5f * v * (1.0f + erff(v * 0.70710678118654752f));
}

DEV int col_remap(int np, int mode) {
  if (mode == 0) return np;
  int d = np & 31, hh = (np >> 5) % 6;
  if (d >= 30) return -1;
  if (mode == 1) { int third = np / 192; return third*180 + hh*30 + d; }
  if (mode == 2) { int half  = np / 192; return half *180 + hh*30 + d; }
  return hh*30 + d;
}

// ---------------------------------------------------------------------------
__global__ __launch_bounds__(256) void pack_gemmw(
    const float* __restrict__ W, _Float16* __restrict__ Wp,
    int K, int N, int nch, int mode, float scale,
    int perLayer, int nlayers, int sstride)
{
  int idx = blockIdx.x * 256 + threadIdx.x;
  if (idx >= perLayer * nlayers) return;
  int layer = idx / perLayer;
  int rem = idx - layer*perLayer;
  int unit = rem >> 11;
  int r2 = rem & 2047;
  int nb = r2 >> 9;
  int lane = (r2 >> 3) & 63;
  int j = r2 & 7;
  int cb = unit / nch, ch = unit - cb*nch;
  int quad = lane >> 4, l16 = lane & 15;
  int np = cb*64 + nb*16 + l16;
  int gk = ch*32 + quad*8 + j;
  float v = 0.f;
  if (gk < K) {
    int sc = col_remap(np, mode);
    if (sc >= 0 && sc < N)
      v = W[(size_t)layer*sstride + (size_t)gk*N + sc] * scale;
  }
  Wp[idx] = (_Float16)v;
}

__global__ __launch_bounds__(256) void pack_bias(
    const float* __restrict__ b, float* __restrict__ bp,
    int N, int Np, int mode, float scale, int nlayers)
{
  int idx = blockIdx.x * 256 + threadIdx.x;
  if (idx >= Np * nlayers) return;
  int layer = idx / Np, np = idx - layer*Np;
  int sc = col_remap(np, mode);
  bp[idx] = (sc >= 0 && sc < N) ? b[layer*N + sc] * scale : 0.f;
}

__global__ __launch_bounds__(256) void pack_convw(
    const float* __restrict__ Wc, _Float16* __restrict__ Wp,
    int IC, int OC, int nch, int perLayer, int nlayers, int sstride)
{
  int idx = blockIdx.x * 256 + threadIdx.x;
  if (idx >= perLayer * nlayers) return;
  int layer = idx / perLayer;
  int rem = idx - layer*perLayer;
  int unit = rem / PKC;
  int w2 = rem - unit*PKC;
  int tap = w2 >> 11;
  int r2 = w2 & 2047;
  int nb = r2 >> 9;
  int lane = (r2 >> 3) & 63;
  int j = r2 & 7;
  int cb = unit / nch, ch = unit - cb*nch;
  int quad = lane >> 4, l16 = lane & 15;
  int oc = cb*64 + nb*16 + l16;
  int gk = ch*32 + quad*8 + j;
  float v = 0.f;
  if (oc < OC && gk < IC)
    v = Wc[(size_t)layer*sstride + ((size_t)oc * IC + gk) * 9 + tap];
  Wp[idx] = (_Float16)v;
}

// ---------------------------------------------------------------------------
// init: X = x_in (fp32), X16 = f16(x_in) (stride 192, padded). 4 rows/block.
// ---------------------------------------------------------------------------
__global__ __launch_bounds__(256) void initx_kernel(
    const float* __restrict__ x_in, float* __restrict__ X,
    _Float16* __restrict__ X16)
{
  int wave = threadIdx.x >> 6, lane = threadIdx.x & 63;
  int r = blockIdx.x * 4 + wave;
  const float* xr = x_in + (size_t)r * C;
  float v0 = xr[lane];
  float v1 = xr[lane + 64];
  float v2 = (lane < 52) ? xr[lane + 128] : 0.f;
  float* xo = X + (size_t)r * C;
  xo[lane] = v0; xo[lane + 64] = v1;
  if (lane < 52) xo[lane + 128] = v2;
  _Float16* m = X16 + (size_t)r * 192;
  m[lane] = (_Float16)v0; m[lane + 64] = (_Float16)v1;
  if (lane < 52) m[lane + 128] = (_Float16)v2;
  if (lane < 12) m[180 + lane] = (_Float16)0.f;
}

// ---------------------------------------------------------------------------
// LayerNorm from f16 X16 (stride 192): 4 rows/block, f16 out stride 192.
// ---------------------------------------------------------------------------
__global__ __launch_bounds__(256) void ln2_kernel(
    const _Float16* __restrict__ Xh, const float* __restrict__ gw,
    const float* __restrict__ gb, _Float16* __restrict__ OUT,
    int mode, int shift)
{
  int wave = threadIdx.x >> 6, lane = threadIdx.x & 63;
  int r = blockIdx.x * 4 + wave;
  int s = (mode == 1) ? win_to_nat(r, shift) : r;
  const _Float16* xr = Xh + (size_t)s * 192;
  float v0 = (float)xr[lane];
  float v1 = (float)xr[lane + 64];
  float v2 = (lane < 52) ? (float)xr[lane + 128] : 0.f;
  float sum = v0 + v1 + v2;
  float sq  = v0*v0 + v1*v1 + v2*v2;
  #pragma unroll
  for (int off = 32; off > 0; off >>= 1) {
    sum += __shfl_down(sum, off);
    sq  += __shfl_down(sq,  off);
  }
  sum = __shfl(sum, 0);
  sq  = __shfl(sq,  0);
  float mu  = sum * (1.f / C);
  float var = sq * (1.f / C) - mu * mu;
  float inv = rsqrtf(var + 1e-5f);
  _Float16* orow = OUT + (size_t)r * 192;
  orow[lane]      = (_Float16)((v0 - mu) * inv * gw[lane]      + gb[lane]);
  orow[lane + 64] = (_Float16)((v1 - mu) * inv * gw[lane + 64] + gb[lane + 64]);
  if (lane < 52)
    orow[lane + 128] = (_Float16)((v2 - mu) * inv * gw[lane + 128] + gb[lane + 128]);
  if (lane < 12) orow[180 + lane] = (_Float16)0.f;
}

// ---------------------------------------------------------------------------
// MFMA f16 GEMM: 128x64 tile; A staged once per 192-wide super-chunk (50 KB
// LDS, stride 200), 6 chunks x 8 MFMA per barrier pair. B frags from global.
// epi: 0 f16 store, 1 gelu f16 store, 2 fp32 residual + X16 mirror.
// ---------------------------------------------------------------------------
__global__ __launch_bounds__(256) void gemm2(
    const _Float16* __restrict__ A, int lda,
    const _Float16* __restrict__ Wp, const float* __restrict__ bias,
    _Float16* __restrict__ O16, int ldo, int nstore,
    float* __restrict__ O32, const float* __restrict__ RES,
    _Float16* __restrict__ XM,
    int K, int nch, int amap, int emap, int epi, int shift)
{
  __shared__ _Float16 As[128][200];
  int tid  = threadIdx.x;
  int lane = tid & 63, wave = tid >> 6;
  int quad = lane >> 4, ln16 = lane & 15;
  int row0 = blockIdx.y * 128;
  int col0 = blockIdx.x * 64;

  f32x4 acc[2][4];
  #pragma unroll
  for (int mt = 0; mt < 2; ++mt)
    #pragma unroll
    for (int nb = 0; nb < 4; ++nb)
      #pragma unroll
      for (int r = 0; r < 4; ++r) acc[mt][nb][r] = 0.f;

  const _Float16* wlane = Wp + (size_t)lane*8;
  int nsc = (K + 191) / 192;

  for (int sc = 0; sc < nsc; ++sc) {
    int kb = sc * 192;
    if (sc) __syncthreads();
    // stage A: 128 rows x 24 segs = 3072 tasks (12 iters)
    #pragma unroll
    for (int i = 0; i < 12; ++i) {
      int task = i*256 + tid;
      int ar = task / 24, seg = task - ar*24;
      int gk = kb + seg*8;
      int gr = row0 + ar;
      int sr = amap ? ocab_src_row(gr) : gr;
      h8 av;
      #pragma unroll
      for (int j = 0; j < 8; ++j) av[j] = (_Float16)0.f;
      if (sr >= 0 && gk < K) {
        const _Float16* ap = A + (size_t)sr*lda + gk;
        if (gk + 8 <= K) av = *(const h8*)ap;
        else {
          #pragma unroll
          for (int j = 0; j < 8; ++j)
            if (gk + j < K) av[j] = ap[j];
        }
      }
      *(h8*)&As[ar][seg*8] = av;
    }
    __syncthreads();
    #pragma unroll
    for (int c = 0; c < 6; ++c) {
      int cglob = sc*6 + c;
      h8 bf[4];
      #pragma unroll
      for (int nb = 0; nb < 4; ++nb)
        bf[nb] = *(const h8*)(wlane + (size_t)(blockIdx.x*nch + cglob)*PKG + (size_t)nb*512);
      h8 af0 = *(const h8*)&As[wave*32 + ln16][c*32 + quad*8];
      h8 af1 = *(const h8*)&As[wave*32 + 16 + ln16][c*32 + quad*8];
      #pragma unroll
      for (int nb = 0; nb < 4; ++nb) {
        acc[0][nb] = __builtin_amdgcn_mfma_f32_16x16x32_f16(af0, bf[nb], acc[0][nb], 0, 0, 0);
        acc[1][nb] = __builtin_amdgcn_mfma_f32_16x16x32_f16(af1, bf[nb], acc[1][nb], 0, 0, 0);
      }
    }
  }

  #pragma unroll
  for (int mt = 0; mt < 2; ++mt)
    #pragma unroll
    for (int r = 0; r < 4; ++r) {
      int m = row0 + wave*32 + mt*16 + quad*4 + r;
      int dst = emap ? win_to_nat(m, shift) : m;
      #pragma unroll
      for (int nb = 0; nb < 4; ++nb) {
        int n = col0 + nb*16 + ln16;
        if (n < nstore) {
          float v = acc[mt][nb][r] + bias[n];
          if (epi == 2) {
            v += RES[(size_t)dst*180 + n];
            O32[(size_t)dst*180 + n] = v;
            XM[(size_t)dst*192 + n] = (_Float16)v;
          } else {
            if (epi == 1) v = gelu_exact(v);
            O16[(size_t)dst*ldo + n] = (_Float16)v;
          }
        }
      }
    }
}

// ---------------------------------------------------------------------------
// MFMA f16 3x3 conv, 2-row tiles (2 image rows x 64 px x 64 oc per block).
// f16 input only (padded strides -> unguarded h8 loads). Halo 4x66 in LDS.
// O16: f16 stride 64 zero-padded; else O32 = acc+bias+RES (+ XM mirror).
// grid = (ceil(OC/64), 288), 256 threads.
// ---------------------------------------------------------------------------
__global__ __launch_bounds__(256) void conv9_mfma(
    const _Float16* __restrict__ Xh, int ldah,
    const _Float16* __restrict__ Wp, const float* __restrict__ bias,
    const float* __restrict__ scale, const float* __restrict__ RES,
    float* __restrict__ O32, _Float16* __restrict__ XM,
    _Float16* __restrict__ O16, int OC, int nch)
{
  __shared__ _Float16 hs[4][66][40];
  int tid  = threadIdx.x;
  int lane = tid & 63, wave = tid >> 6;
  int quad = lane >> 4, ln16 = lane & 15;
  int by = blockIdx.y;
  int rp = by / 3, wb = by - rp*3;
  int h0 = rp*2;
  int w0 = wb*64;
  int col0 = blockIdx.x * 64;

  f32x4 acc[2][4];
  #pragma unroll
  for (int mt = 0; mt < 2; ++mt)
    #pragma unroll
    for (int nb = 0; nb < 4; ++nb)
      #pragma unroll
      for (int r = 0; r < 4; ++r) acc[mt][nb][r] = 0.f;

  for (int c = 0; c < nch; ++c) {
    int k0 = c * 32;
    if (c) __syncthreads();
    // stage halo: 4 rows x 66 px x 4 segs = 1056 tasks
    for (int idx = tid; idx < 4*66*4; idx += 256) {
      int r    = idx / 264;
      int rem  = idx - r*264;
      int px   = rem >> 2;
      int ks   = (rem & 3) * 8;
      int gh = h0 - 1 + r, gw = w0 - 1 + px;
      h8 hv;
      #pragma unroll
      for (int j = 0; j < 8; ++j) hv[j] = (_Float16)0.f;
      if ((unsigned)gh < (unsigned)HH && (unsigned)gw < (unsigned)WW) {
        hv = *(const h8*)(Xh + (size_t)(gh*WW + gw) * ldah + k0 + ks);
        if (scale) {
          #pragma unroll
          for (int j = 0; j < 8; ++j)
            hv[j] = (_Float16)((float)hv[j] * scale[k0 + ks + j]);
        }
      }
      *(h8*)&hs[r][px][ks] = hv;
    }
    __syncthreads();

    const _Float16* wpc = Wp + (size_t)(blockIdx.x*nch + c) * PKC + (size_t)lane*8;
    h8 bf[4];
    #pragma unroll
    for (int nb = 0; nb < 4; ++nb)
      bf[nb] = *(const h8*)(wpc + (size_t)nb*512);
    #pragma unroll
    for (int tap = 0; tap < 9; ++tap) {
      h8 bfn[4];
      if (tap < 8) {
        #pragma unroll
        for (int nb = 0; nb < 4; ++nb)
          bfn[nb] = *(const h8*)(wpc + (size_t)(tap+1)*2048 + (size_t)nb*512);
      }
      int dyy = tap / 3, dxt = tap - dyy*3;
      h8 af0 = *(const h8*)&hs[dyy][wave*16 + ln16 + dxt][quad*8];
      h8 af1 = *(const h8*)&hs[dyy + 1][wave*16 + ln16 + dxt][quad*8];
      #pragma unroll
      for (int nb = 0; nb < 4; ++nb) {
        acc[0][nb] = __builtin_amdgcn_mfma_f32_16x16x32_f16(af0, bf[nb], acc[0][nb], 0, 0, 0);
        acc[1][nb] = __builtin_amdgcn_mfma_f32_16x16x32_f16(af1, bf[nb], acc[1][nb], 0, 0, 0);
      }
      if (tap < 8) {
        #pragma unroll
        for (int nb = 0; nb < 4; ++nb) bf[nb] = bfn[nb];
      }
    }
  }

  #pragma unroll
  for (int mt = 0; mt < 2; ++mt)
    #pragma unroll
    for (int r = 0; r < 4; ++r) {
      int p = (h0 + mt)*WW + w0 + wave*16 + quad*4 + r;
      #pragma unroll
      for (int nb = 0; nb < 4; ++nb) {
        int oc = col0 + nb*16 + ln16;
        if (O16) {
          float v = (oc < OC) ? acc[mt][nb][r] + bias[oc] : 0.f;
          O16[(size_t)p*64 + oc] = (_Float16)v;
        } else if (oc < OC) {
          float v = acc[mt][nb][r] + bias[oc] + RES[(size_t)p * OC + oc];
          O32[(size_t)p * OC + oc] = v;
          if (XM) XM[(size_t)p*192 + oc] = (_Float16)v;
        }
      }
    }
}

// ---------------------------------------------------------------------------
// MFMA window attention, f16 QKV (stride 576, heads padded to 32).
// ---------------------------------------------------------------------------
__global__ __launch_bounds__(256) void win_attn_mfma(
    const _Float16* __restrict__ QKV, const float* __restrict__ relb,
    _Float16* __restrict__ OUT, int shift)
{
  __shared__ _Float16 Kf[256][40];
  __shared__ _Float16 Vt[32][264];
  __shared__ _Float16 rbs[962];
  __shared__ unsigned char rg[256];
  int b = blockIdx.x;
  int w = b / HEADS, hd = b - (b / HEADS)*HEADS;
  int tid = threadIdx.x, lane = tid & 63, wave = tid >> 6;
  int quad = lane >> 4, ln16 = lane & 15;
  const _Float16* base = QKV + (size_t)(w*NTW)*576;

  #pragma unroll
  for (int i = 0; i < 4; ++i) {
    int task = i*256 + tid;
    int row = task >> 2, seg = (task & 3) * 8;
    *(h8*)&Kf[row][seg] = *(const h8*)(base + (size_t)row*576 + 192 + hd*32 + seg);
    h8 hv = *(const h8*)(base + (size_t)row*576 + 384 + hd*32 + seg);
    #pragma unroll
    for (int j = 0; j < 8; ++j) Vt[seg + j][row] = hv[j];
  }
  for (int i = tid; i < 961; i += 256) rbs[i] = (_Float16)relb[i*HEADS + hd];
  if (shift > 0) {
    int wh = w / NWW, ww = w - wh*NWW;
    int rh = wh*WS + (tid >> 4), rw = ww*WS + (tid & 15);
    int regh = (rh < HH - WS) ? 0 : (rh < HH - 8 ? 1 : 2);
    int regw = (rw < WW - WS) ? 0 : (rw < WW - 8 ? 1 : 2);
    rg[tid] = (unsigned char)(regh*3 + regw);
  }

  h8 bq[4];
  #pragma unroll
  for (int qi = 0; qi < 4; ++qi) {
    int q = wave*64 + qi*16 + ln16;
    bq[qi] = *(const h8*)(base + (size_t)q*576 + hd*32 + quad*8);
  }
  __syncthreads();

  float mrun[4], lrun[4];
  f32x4 accO[4][2];
  #pragma unroll
  for (int qi = 0; qi < 4; ++qi) {
    mrun[qi] = -1e30f; lrun[qi] = 0.f;
    #pragma unroll
    for (int r = 0; r < 4; ++r) { accO[qi][0][r] = 0.f; accO[qi][1][r] = 0.f; }
  }
  int rgq[4] = {0,0,0,0};
  if (shift > 0) {
    #pragma unroll
    for (int qi = 0; qi < 4; ++qi) rgq[qi] = rg[wave*64 + qi*16 + ln16];
  }
  const f32x4 zero4 = {0.f,0.f,0.f,0.f};

  for (int kb = 0; kb < 4; ++kb) {
    f32x4 st[4][4];
    #pragma unroll
    for (int kt = 0; kt < 4; ++kt) {
      h8 ak = *(const h8*)&Kf[kb*64 + kt*16 + ln16][quad*8];
      #pragma unroll
      for (int qi = 0; qi < 4; ++qi)
        st[kt][qi] = __builtin_amdgcn_mfma_f32_16x16x32_f16(ak, bq[qi], zero4, 0, 0, 0);
    }
    #pragma unroll
    for (int qi = 0; qi < 4; ++qi) {
      int q = wave*64 + qi*16 + ln16;
      int qrr = q >> 4, qcc = q & 15;
      float bmax = -1e30f;
      #pragma unroll
      for (int kt = 0; kt < 4; ++kt) {
        int bidx0 = (qrr - (kb*4 + kt) + 15)*31 + qcc + 15 - quad*4;
        #pragma unroll
        for (int r = 0; r < 4; ++r) {
          float s = st[kt][qi][r] + (float)rbs[bidx0 - r];
          if (shift > 0) {
            int key = kb*64 + kt*16 + quad*4 + r;
            if (rg[key] != rgq[qi]) s -= 100.f;
          }
          st[kt][qi][r] = s;
          bmax = fmaxf(bmax, s);
        }
      }
      bmax = fmaxf(bmax, __shfl_xor(bmax, 16));
      bmax = fmaxf(bmax, __shfl_xor(bmax, 32));
      float mnew  = fmaxf(mrun[qi], bmax);
      float alpha = __expf(mrun[qi] - mnew);
      mrun[qi] = mnew;
      float ps = 0.f;
      #pragma unroll
      for (int kt = 0; kt < 4; ++kt)
        #pragma unroll
        for (int r = 0; r < 4; ++r) {
          float p = __expf(st[kt][qi][r] - mnew);
          st[kt][qi][r] = p; ps += p;
        }
      ps += __shfl_xor(ps, 16);
      ps += __shfl_xor(ps, 32);
      lrun[qi] = lrun[qi]*alpha + ps;
      #pragma unroll
      for (int r = 0; r < 4; ++r) {
        float fr = __shfl(alpha, quad*4 + r);
        accO[qi][0][r] *= fr;
        accO[qi][1][r] *= fr;
      }
    }
    #pragma unroll
    for (int kt = 0; kt < 4; ++kt) {
      int kbase = kb*64 + kt*16 + quad*4;
      h4 bv0 = *(const h4*)&Vt[ln16][kbase];
      h4 bv1 = *(const h4*)&Vt[16 + ln16][kbase];
      #pragma unroll
      for (int qi = 0; qi < 4; ++qi) {
        h4 ap;
        #pragma unroll
        for (int j = 0; j < 4; ++j) ap[j] = (_Float16)st[kt][qi][j];
        accO[qi][0] = __builtin_amdgcn_mfma_f32_16x16x16f16(ap, bv0, accO[qi][0], 0, 0, 0);
        accO[qi][1] = __builtin_amdgcn_mfma_f32_16x16x16f16(ap, bv1, accO[qi][1], 0, 0, 0);
      }
    }
  }

  #pragma unroll
  for (int qi = 0; qi < 4; ++qi) {
    float linv = 1.f / lrun[qi];
    #pragma unroll
    for (int r = 0; r < 4; ++r) {
      float fr = __shfl(linv, quad*4 + r);
      int q = wave*64 + qi*16 + quad*4 + r;
      _Float16* o = OUT + (size_t)(w*NTW + q)*192 + hd*HD;
      o[ln16] = (_Float16)(accO[qi][0][r] * fr);
      if (ln16 < HD - 16) o[16 + ln16] = (_Float16)(accO[qi][1][r] * fr);
    }
  }
}

// ---------------------------------------------------------------------------
// MFMA OCAB attention, f16 Q (stride 192, pre-scaled) + f16 KV (stride 384).
// ---------------------------------------------------------------------------
__global__ __launch_bounds__(256) void ocab_attn_mfma(
    const _Float16* __restrict__ Q, const _Float16* __restrict__ KV,
    _Float16* __restrict__ OUT)
{
  constexpr int CH = 192;
  __shared__ _Float16 Kf[CH][40];
  __shared__ _Float16 Vt[32][200];
  int b = blockIdx.x;
  int w = b / HEADS, hd = b - (b / HEADS)*HEADS;
  int tid = threadIdx.x, lane = tid & 63, wave = tid >> 6;
  int quad = lane >> 4, ln16 = lane & 15;

  h8 bq[4];
  #pragma unroll
  for (int qi = 0; qi < 4; ++qi) {
    int q = wave*64 + qi*16 + ln16;
    bq[qi] = *(const h8*)(Q + (size_t)(w*NTW + q)*192 + hd*32 + quad*8);
  }

  float mrun[4], lrun[4];
  f32x4 accO[4][2];
  #pragma unroll
  for (int qi = 0; qi < 4; ++qi) {
    mrun[qi] = -1e30f; lrun[qi] = 0.f;
    #pragma unroll
    for (int r = 0; r < 4; ++r) { accO[qi][0][r] = 0.f; accO[qi][1][r] = 0.f; }
  }
  const f32x4 zero4 = {0.f,0.f,0.f,0.f};

  for (int ch = 0; ch < 3; ++ch) {
    __syncthreads();
    #pragma unroll
    for (int i = 0; i < 3; ++i) {
      int task = i*256 + tid;
      int row = task >> 2, seg = (task & 3) * 8;
      const _Float16* kvr = KV + (size_t)(w*NKV + ch*CH + row)*384;
      *(h8*)&Kf[row][seg] = *(const h8*)(kvr + hd*32 + seg);
      h8 hv = *(const h8*)(kvr + 192 + hd*32 + seg);
      #pragma unroll
      for (int j = 0; j < 8; ++j) Vt[seg + j][row] = hv[j];
    }
    __syncthreads();

    for (int kb = 0; kb < 3; ++kb) {
      f32x4 st[4][4];
      #pragma unroll
      for (int kt = 0; kt < 4; ++kt) {
        h8 ak = *(const h8*)&Kf[kb*64 + kt*16 + ln16][quad*8];
        #pragma unroll
        for (int qi = 0; qi < 4; ++qi)
          st[kt][qi] = __builtin_amdgcn_mfma_f32_16x16x32_f16(ak, bq[qi], zero4, 0, 0, 0);
      }
      #pragma unroll
      for (int qi = 0; qi < 4; ++qi) {
        float bmax = -1e30f;
        #pragma unroll
        for (int kt = 0; kt < 4; ++kt)
          #pragma unroll
          for (int r = 0; r < 4; ++r) bmax = fmaxf(bmax, st[kt][qi][r]);
        bmax = fmaxf(bmax, __shfl_xor(bmax, 16));
        bmax = fmaxf(bmax, __shfl_xor(bmax, 32));
        float mnew  = fmaxf(mrun[qi], bmax);
        float alpha = __expf(mrun[qi] - mnew);
        mrun[qi] = mnew;
        float ps = 0.f;
        #pragma unroll
        for (int kt = 0; kt < 4; ++kt)
          #pragma unroll
          for (int r = 0; r < 4; ++r) {
            float p = __expf(st[kt][qi][r] - mnew);
            st[kt][qi][r] = p; ps += p;
          }
        ps += __shfl_xor(ps, 16);
        ps += __shfl_xor(ps, 32);
        lrun[qi] = lrun[qi]*alpha + ps;
        #pragma unroll
        for (int r = 0; r < 4; ++r) {
          float fr = __shfl(alpha, quad*4 + r);
          accO[qi][0][r] *= fr;
          accO[qi][1][r] *= fr;
        }
      }
      #pragma unroll
      for (int kt = 0; kt < 4; ++kt) {
        int kbase = kb*64 + kt*16 + quad*4;
        h4 bv0 = *(const h4*)&Vt[ln16][kbase];
        h4 bv1 = *(const h4*)&Vt[16 + ln16][kbase];
        #pragma unroll
        for (int qi = 0; qi < 4; ++qi) {
          h4 ap;
          #pragma unroll
          for (int j = 0; j < 4; ++j) ap[j] = (_Float16)st[kt][qi][j];
          accO[qi][0] = __builtin_amdgcn_mfma_f32_16x16x16f16(ap, bv0, accO[qi][0], 0, 0, 0);
          accO[qi][1] = __builtin_amdgcn_mfma_f32_16x16x16f16(ap, bv1, accO[qi][1], 0, 0, 0);
        }
      }
    }
  }

  #pragma unroll
  for (int qi = 0; qi < 4; ++qi) {
    float linv = 1.f / lrun[qi];
    #pragma unroll
    for (int r = 0; r < 4; ++r) {
      float fr = __shfl(linv, quad*4 + r);
      int q = wave*64 + qi*16 + quad*4 + r;
      _Float16* o = OUT + (size_t)(w*NTW + q)*192 + hd*HD;
      o[ln16] = (_Float16)(accO[qi][0][r] * fr);
      if (ln16 < HD - 16) o[16 + ln16] = (_Float16)(accO[qi][1][r] * fr);
    }
  }
}

// ---------------------------------------------------------------------------
__global__ __launch_bounds__(256) void colsum_kernel(
    const _Float16* __restrict__ COMP, float* __restrict__ S)
{
  int tid = threadIdx.x;
  int seg = tid & 7, rb = tid >> 3;
  int row0 = blockIdx.x * 128;
  float a[8] = {};
  #pragma unroll
  for (int i = 0; i < 4; ++i) {
    int row = row0 + i*32 + rb;
    h8 v = *(const h8*)(COMP + (size_t)row*64 + seg*8);
    #pragma unroll
    for (int j = 0; j < 8; ++j) a[j] += (float)v[j];
  }
  __shared__ float sA[64];
  if (tid < 64) sA[tid] = 0.f;
  __syncthreads();
  #pragma unroll
  for (int j = 0; j < 8; ++j) atomicAdd(&sA[seg*8 + j], a[j]);
  __syncthreads();
  if (tid < 60) atomicAdd(&S[tid], sA[tid]);
}

__global__ __launch_bounds__(64) void se_kernel(
    const float* __restrict__ S, const float* __restrict__ w1,
    const float* __restrict__ b1, const float* __restrict__ w2,
    const float* __restrict__ b2, float* __restrict__ G)
{
  __shared__ float hid[CSE];
  int t = threadIdx.x;
  if (t < CSE) {
    float a = b1[t];
    for (int c = 0; c < CCH; ++c) a += (S[c] * (1.f/NT)) * w1[c * CSE + t];
    hid[t] = fmaxf(a, 0.f);
  }
  __syncthreads();
  if (t < CCH) {
    float a = b2[t];
    #pragma unroll
    for (int j = 0; j < CSE; ++j) a += hid[j] * w2[j * CCH + t];
    G[t] = 1.f / (1.f + __expf(-a));
  }
}

// ---------------------------------------------------------------------------

extern "C" void kernel_launch(void* const* d_in, const int* in_sizes, int n_in,
                              void* d_out, int out_size, void* d_ws, size_t ws_size,
                              hipStream_t stream) {
  const float* x_in   = (const float*)d_in[0];
  const float* n1w    = (const float*)d_in[1];
  const float* n1b    = (const float*)d_in[2];
  const float* qkvw   = (const float*)d_in[3];
  const float* qkvb   = (const float*)d_in[4];
  const float* relb   = (const float*)d_in[5];
  const float* projw  = (const float*)d_in[6];
  const float* projb  = (const float*)d_in[7];
  const float* ccw    = (const float*)d_in[8];
  const float* ccb    = (const float*)d_in[9];
  const float* ca1w   = (const float*)d_in[10];
  const float* ca1b   = (const float*)d_in[11];
  const float* ca2w   = (const float*)d_in[12];
  const float* ca2b   = (const float*)d_in[13];
  const float* cew    = (const float*)d_in[14];
  const float* ceb    = (const float*)d_in[15];
  const float* n2w    = (const float*)d_in[16];
  const float* n2b    = (const float*)d_in[17];
  const float* m1w    = (const float*)d_in[18];
  const float* m1b    = (const float*)d_in[19];
  const float* m2w    = (const float*)d_in[20];
  const float* m2b    = (const float*)d_in[21];
  const float* onw    = (const float*)d_in[22];
  const float* onb    = (const float*)d_in[23];
  const float* oqw    = (const float*)d_in[24];
  const float* oqb    = (const float*)d_in[25];
  const float* okvw   = (const float*)d_in[26];
  const float* okvb   = (const float*)d_in[27];
  const float* opw    = (const float*)d_in[28];
  const float* opb    = (const float*)d_in[29];
  const float* convw  = (const float*)d_in[30];
  const float* convb  = (const float*)d_in[31];

  float* ws   = (float*)d_ws;
  float*     X    = ws + OFF_X;
  _Float16*  A    = (_Float16*)(ws + OFF_A);
  _Float16*  Bq   = (_Float16*)(ws + OFF_B);
  _Float16*  COMP = (_Float16*)(ws + OFF_COMP);
  float*     S    = ws + OFF_S;
  float*     G    = ws + OFF_G;
  _Float16*  QKV  = (_Float16*)(ws + OFF_QKV);
  _Float16*  PK   = (_Float16*)(ws + OFF_PK);
  float*     PB   = ws + OFF_PB;
  _Float16*  X16  = (_Float16*)(ws + OFF_X16);

  float* qkvB = PB;
  float* oqB  = PB + 6*576;
  float* okvB = oqB + 192;

  const float scl = 0.18257418583505536f;

  initx_kernel<<<NT/4, 256, 0, stream>>>(x_in, X, X16);

  #define GRID(n) dim3(((n)+255)/256)
  pack_gemmw<<<GRID(6*QKV_PL), 256, 0, stream>>>(qkvw, PK+PO_QKV, 180, 540, 6, 1, 1.f, QKV_PL, 6, 180*540);
  pack_gemmw<<<GRID(6*PROJ_PL),256, 0, stream>>>(projw, PK+PO_PROJ,180, 180, 6, 0, 1.f, PROJ_PL,6, 180*180);
  pack_gemmw<<<GRID(6*M1_PL), 256, 0, stream>>>(m1w,  PK+PO_M1,  180, 360, 6, 0, 1.f, M1_PL,  6, 180*360);
  pack_gemmw<<<GRID(6*M2_PL), 256, 0, stream>>>(m2w,  PK+PO_M2,  360, 180,12, 0, 1.f, M2_PL,  6, 360*180);
  pack_gemmw<<<GRID(OQ_PL),   256, 0, stream>>>(oqw,  PK+PO_OQ,  180, 180, 6, 3, scl, OQ_PL,  1, 0);
  pack_gemmw<<<GRID(OKV_PL),  256, 0, stream>>>(okvw, PK+PO_OKV, 180, 360, 6, 2, 1.f, OKV_PL, 1, 0);
  pack_gemmw<<<GRID(OP_PL),   256, 0, stream>>>(opw,  PK+PO_OP,  180, 180, 6, 0, 1.f, OP_PL,  1, 0);
  pack_convw<<<GRID(6*CC_PL), 256, 0, stream>>>(ccw,  PK+PO_CC,  180,  60, 6, CC_PL, 6, 60*180*9);
  pack_convw<<<GRID(6*CE_PL), 256, 0, stream>>>(cew,  PK+PO_CE,   60, 180, 2, CE_PL, 6, 180*60*9);
  pack_convw<<<GRID(FIN_PL),  256, 0, stream>>>(convw,PK+PO_FIN, 180, 180, 6, FIN_PL,1, 0);
  pack_bias<<<GRID(6*576), 256, 0, stream>>>(qkvb, qkvB, 540, 576, 1, 1.f, 6);
  pack_bias<<<GRID(192),   256, 0, stream>>>(oqb,  oqB,  180, 192, 3, scl, 1);
  pack_bias<<<GRID(384),   256, 0, stream>>>(okvb, okvB, 360, 384, 2, 1.f, 1);

  const int MB128 = NT / 128;   // 288
  const int CB    = 288;        // conv 2-row blocks

  for (int i = 0; i < DEPTH; ++i) {
    int shift = (i % 2 == 0) ? 0 : WS / 2;
    ln2_kernel<<<NT/4, 256, 0, stream>>>(X16, n1w + i*C, n1b + i*C, A, 1, shift);
    gemm2<<<dim3(9, MB128), 256, 0, stream>>>(
        A, 192, PK+PO_QKV + (size_t)i*QKV_PL, qkvB + i*576,
        QKV, 576, 576, nullptr, nullptr, nullptr, 180, 6, 0, 0, 0, 0);
    win_attn_mfma<<<NWIN*HEADS, 256, 0, stream>>>(
        QKV, relb + (size_t)i*961*HEADS, A, shift);
    gemm2<<<dim3(3, MB128), 256, 0, stream>>>(
        A, 192, PK+PO_PROJ + (size_t)i*PROJ_PL, projb + i*C,
        nullptr, 0, 180, X, X, X16, 180, 6, 0, 1, 2, shift);
    conv9_mfma<<<dim3(1, CB), 256, 0, stream>>>(
        X16, 192, PK+PO_CC + (size_t)i*CC_PL, ccb + i*CCH,
        nullptr, nullptr, nullptr, nullptr, COMP, 60, 6);
    (void)hipMemsetAsync(S, 0, 64*sizeof(float), stream);
    colsum_kernel<<<288, 256, 0, stream>>>(COMP, S);
    se_kernel<<<1, 64, 0, stream>>>(
        S, ca1w + (size_t)i*CCH*CSE, ca1b + (size_t)i*CSE,
        ca2w + (size_t)i*CSE*CCH, ca2b + (size_t)i*CCH, G);
    conv9_mfma<<<dim3(3, CB), 256, 0, stream>>>(
        COMP, 64, PK+PO_CE + (size_t)i*CE_PL, ceb + i*C,
        G, X, X, X16, nullptr, 180, 2);
    ln2_kernel<<<NT/4, 256, 0, stream>>>(X16, n2w + i*C, n2b + i*C, A, 0, 0);
    gemm2<<<dim3(6, MB128), 256, 0, stream>>>(
        A, 192, PK+PO_M1 + (size_t)i*M1_PL, m1b + i*HID,
        QKV, 384, 360, nullptr, nullptr, nullptr, 180, 6, 0, 0, 1, 0);
    gemm2<<<dim3(3, MB128), 256, 0, stream>>>(
        QKV, 384, PK+PO_M2 + (size_t)i*M2_PL, m2b + i*C,
        nullptr, 0, 180, X, X, X16, 360, 12, 0, 0, 2, 0);
  }

  // ---- OCAB ----
  ln2_kernel<<<NT/4, 256, 0, stream>>>(X16, onw, onb, A, 1, 0);
  gemm2<<<dim3(3, MB128), 256, 0, stream>>>(
      A, 192, PK+PO_OQ, oqB, Bq, 192, 192, nullptr, nullptr, nullptr, 180, 6, 0, 0, 0, 0);
  gemm2<<<dim3(6, NWIN*NKV/128), 256, 0, stream>>>(
      A, 192, PK+PO_OKV, okvB, QKV, 384, 384, nullptr, nullptr, nullptr, 180, 6, 1, 0, 0, 0);
  ocab_attn_mfma<<<NWIN*HEADS, 256, 0, stream>>>(Bq, QKV, A);
  gemm2<<<dim3(3, MB128), 256, 0, stream>>>(
      A, 192, PK+PO_OP, opb, nullptr, 0, 180, X, X, X16, 180, 6, 0, 1, 2, 0);

  // ---- final conv + global shortcut -> d_out ----
  conv9_mfma<<<dim3(3, CB), 256, 0, stream>>>(
      X16, 192, PK+PO_FIN, convb, nullptr, x_in,
      (float*)d_out, nullptr, nullptr, 180, 6);
}

// Round 9
// 2469.308 us; speedup vs baseline: 1.3172x; 1.3172x over previous
//
#include <hip/hip_runtime.h>
#include <math.h>

// ---------------------------------------------------------------------------
// HAT block — fp32 residual + f16 mirror (X16), f16 activations, MFMA
// everywhere. Weights pre-packed lane-contiguous; B-frags global->VGPR.
// Conv: 2-row halo tiles. GEMM: 32-wide K chunks, 10 KB LDS (occupancy!).
// ---------------------------------------------------------------------------

#define DEV __device__ __forceinline__

constexpr int HH   = 192;
constexpr int WW   = 192;
constexpr int NT   = HH * WW;     // 36864
constexpr int C    = 180;
constexpr int HEADS= 6;
constexpr int HD   = 30;
constexpr int WS   = 16;
constexpr int NWW  = WW / WS;     // 12
constexpr int NWIN = 144;
constexpr int NTW  = 256;
constexpr int OWS  = 24;
constexpr int NKV  = OWS*OWS;     // 576
constexpr int CCH  = 60;
constexpr int CSE  = 6;
constexpr int HID  = 360;
constexpr int DEPTH= 6;

typedef _Float16 h8   __attribute__((ext_vector_type(8)));
typedef _Float16 h4   __attribute__((ext_vector_type(4)));
typedef float    f32x4 __attribute__((ext_vector_type(4)));

constexpr int PKG = 2048;            // gemm pack unit: [nb4][lane64][j8]
constexpr int PKC = 18432;           // conv pack unit: [tap9][nb4][lane64][j8]

constexpr int QKV_PL = 9*6*PKG;
constexpr int PROJ_PL= 3*6*PKG;
constexpr int M1_PL  = 6*6*PKG;
constexpr int M2_PL  = 3*12*PKG;
constexpr int OQ_PL  = 3*6*PKG;
constexpr int OKV_PL = 6*6*PKG;
constexpr int OP_PL  = 3*6*PKG;
constexpr int CC_PL  = 1*6*PKC;
constexpr int CE_PL  = 3*2*PKC;
constexpr int FIN_PL = 3*6*PKC;

constexpr size_t PO_QKV = 0;
constexpr size_t PO_PROJ= PO_QKV + 6ull*QKV_PL;
constexpr size_t PO_M1  = PO_PROJ+ 6ull*PROJ_PL;
constexpr size_t PO_M2  = PO_M1  + 6ull*M1_PL;
constexpr size_t PO_OQ  = PO_M2  + 6ull*M2_PL;
constexpr size_t PO_OKV = PO_OQ  + OQ_PL;
constexpr size_t PO_OP  = PO_OKV + OKV_PL;
constexpr size_t PO_CC  = PO_OP  + OP_PL;
constexpr size_t PO_CE  = PO_CC  + 6ull*CC_PL;
constexpr size_t PO_FIN = PO_CE  + 6ull*CE_PL;
constexpr size_t PK_HALFS = PO_FIN + FIN_PL;

// workspace offsets (floats)
constexpr size_t OFF_X    = 0;                          // X fp32 NT*180
constexpr size_t OFF_A    = OFF_X    + (size_t)NT*C;    // A f16 stride 192
constexpr size_t OFF_B    = OFF_A    + (size_t)NT*C;    // Bq f16 stride 192
constexpr size_t OFF_COMP = OFF_B    + (size_t)NT*C;    // COMP f16 stride 64
constexpr size_t OFF_S    = OFF_COMP + (size_t)NT*CCH;
constexpr size_t OFF_G    = OFF_S    + 64;
constexpr size_t OFF_QKV  = OFF_G    + 64;              // QKV/KV/GELU f16
constexpr size_t OFF_PK   = OFF_QKV  + 16000000;
constexpr size_t OFF_PB   = OFF_PK   + PK_HALFS/2 + 8;
constexpr size_t OFF_X16  = OFF_PB   + 4096;            // X16 f16 stride 192

DEV int win_to_nat(int r, int shift) {
  int w   = r >> 8;
  int pos = r & 255;
  int wh = w / NWW, ww = w - wh*NWW;
  int rh = wh*WS + (pos >> 4);
  int rw = ww*WS + (pos & 15);
  int sh = rh + shift; if (sh >= HH) sh -= HH;
  int sw = rw + shift; if (sw >= WW) sw -= WW;
  return sh*WW + sw;
}

DEV int ocab_src_row(int gr) {
  int w = gr / NKV;
  int t = gr - w*NKV;
  int wh = w / NWW, ww = w - wh*NWW;
  int i = t / OWS, j = t - i*OWS;
  int gh = wh*WS - 4 + i;
  int gw = ww*WS - 4 + j;
  if ((unsigned)gh >= (unsigned)HH || (unsigned)gw >= (unsigned)WW) return -1;
  return (((gh >> 4)*NWW + (gw >> 4)) << 8) + ((gh & 15) << 4) + (gw & 15);
}

DEV float gelu_exact(float v) {
  return 0.5f * v * (1.0f + erff(v * 0.70710678118654752f));
}

DEV int col_remap(int np, int mode) {
  if (mode == 0) return np;
  int d = np & 31, hh = (np >> 5) % 6;
  if (d >= 30) return -1;
  if (mode == 1) { int third = np / 192; return third*180 + hh*30 + d; }
  if (mode == 2) { int half  = np / 192; return half *180 + hh*30 + d; }
  return hh*30 + d;
}

// ---------------------------------------------------------------------------
__global__ __launch_bounds__(256) void pack_gemmw(
    const float* __restrict__ W, _Float16* __restrict__ Wp,
    int K, int N, int nch, int mode, float scale,
    int perLayer, int nlayers, int sstride)
{
  int idx = blockIdx.x * 256 + threadIdx.x;
  if (idx >= perLayer * nlayers) return;
  int layer = idx / perLayer;
  int rem = idx - layer*perLayer;
  int unit = rem >> 11;
  int r2 = rem & 2047;
  int nb = r2 >> 9;
  int lane = (r2 >> 3) & 63;
  int j = r2 & 7;
  int cb = unit / nch, ch = unit - cb*nch;
  int quad = lane >> 4, l16 = lane & 15;
  int np = cb*64 + nb*16 + l16;
  int gk = ch*32 + quad*8 + j;
  float v = 0.f;
  if (gk < K) {
    int sc = col_remap(np, mode);
    if (sc >= 0 && sc < N)
      v = W[(size_t)layer*sstride + (size_t)gk*N + sc] * scale;
  }
  Wp[idx] = (_Float16)v;
}

__global__ __launch_bounds__(256) void pack_bias(
    const float* __restrict__ b, float* __restrict__ bp,
    int N, int Np, int mode, float scale, int nlayers)
{
  int idx = blockIdx.x * 256 + threadIdx.x;
  if (idx >= Np * nlayers) return;
  int layer = idx / Np, np = idx - layer*Np;
  int sc = col_remap(np, mode);
  bp[idx] = (sc >= 0 && sc < N) ? b[layer*N + sc] * scale : 0.f;
}

__global__ __launch_bounds__(256) void pack_convw(
    const float* __restrict__ Wc, _Float16* __restrict__ Wp,
    int IC, int OC, int nch, int perLayer, int nlayers, int sstride)
{
  int idx = blockIdx.x * 256 + threadIdx.x;
  if (idx >= perLayer * nlayers) return;
  int layer = idx / perLayer;
  int rem = idx - layer*perLayer;
  int unit = rem / PKC;
  int w2 = rem - unit*PKC;
  int tap = w2 >> 11;
  int r2 = w2 & 2047;
  int nb = r2 >> 9;
  int lane = (r2 >> 3) & 63;
  int j = r2 & 7;
  int cb = unit / nch, ch = unit - cb*nch;
  int quad = lane >> 4, l16 = lane & 15;
  int oc = cb*64 + nb*16 + l16;
  int gk = ch*32 + quad*8 + j;
  float v = 0.f;
  if (oc < OC && gk < IC)
    v = Wc[(size_t)layer*sstride + ((size_t)oc * IC + gk) * 9 + tap];
  Wp[idx] = (_Float16)v;
}

// ---------------------------------------------------------------------------
// init: X = x_in (fp32), X16 = f16(x_in) (stride 192, padded). 4 rows/block.
// ---------------------------------------------------------------------------
__global__ __launch_bounds__(256) void initx_kernel(
    const float* __restrict__ x_in, float* __restrict__ X,
    _Float16* __restrict__ X16)
{
  int wave = threadIdx.x >> 6, lane = threadIdx.x & 63;
  int r = blockIdx.x * 4 + wave;
  const float* xr = x_in + (size_t)r * C;
  float v0 = xr[lane];
  float v1 = xr[lane + 64];
  float v2 = (lane < 52) ? xr[lane + 128] : 0.f;
  float* xo = X + (size_t)r * C;
  xo[lane] = v0; xo[lane + 64] = v1;
  if (lane < 52) xo[lane + 128] = v2;
  _Float16* m = X16 + (size_t)r * 192;
  m[lane] = (_Float16)v0; m[lane + 64] = (_Float16)v1;
  if (lane < 52) m[lane + 128] = (_Float16)v2;
  if (lane < 12) m[180 + lane] = (_Float16)0.f;
}

// ---------------------------------------------------------------------------
// LayerNorm from f16 X16 (stride 192): 4 rows/block, f16 out stride 192.
// ---------------------------------------------------------------------------
__global__ __launch_bounds__(256) void ln2_kernel(
    const _Float16* __restrict__ Xh, const float* __restrict__ gw,
    const float* __restrict__ gb, _Float16* __restrict__ OUT,
    int mode, int shift)
{
  int wave = threadIdx.x >> 6, lane = threadIdx.x & 63;
  int r = blockIdx.x * 4 + wave;
  int s = (mode == 1) ? win_to_nat(r, shift) : r;
  const _Float16* xr = Xh + (size_t)s * 192;
  float v0 = (float)xr[lane];
  float v1 = (float)xr[lane + 64];
  float v2 = (lane < 52) ? (float)xr[lane + 128] : 0.f;
  float sum = v0 + v1 + v2;
  float sq  = v0*v0 + v1*v1 + v2*v2;
  #pragma unroll
  for (int off = 32; off > 0; off >>= 1) {
    sum += __shfl_down(sum, off);
    sq  += __shfl_down(sq,  off);
  }
  sum = __shfl(sum, 0);
  sq  = __shfl(sq,  0);
  float mu  = sum * (1.f / C);
  float var = sq * (1.f / C) - mu * mu;
  float inv = rsqrtf(var + 1e-5f);
  _Float16* orow = OUT + (size_t)r * 192;
  orow[lane]      = (_Float16)((v0 - mu) * inv * gw[lane]      + gb[lane]);
  orow[lane + 64] = (_Float16)((v1 - mu) * inv * gw[lane + 64] + gb[lane + 64]);
  if (lane < 52)
    orow[lane + 128] = (_Float16)((v2 - mu) * inv * gw[lane + 128] + gb[lane + 128]);
  if (lane < 12) orow[180 + lane] = (_Float16)0.f;
}

// ---------------------------------------------------------------------------
// MFMA f16 GEMM: 128x64 tile, 32-wide K chunks, As 10 KB LDS (high occupancy).
// B frags direct from global (packed lane-contiguous).
// epi: 0 f16 store, 1 gelu f16 store, 2 fp32 residual + X16 mirror.
// ---------------------------------------------------------------------------
__global__ __launch_bounds__(256) void gemm2(
    const _Float16* __restrict__ A, int lda,
    const _Float16* __restrict__ Wp, const float* __restrict__ bias,
    _Float16* __restrict__ O16, int ldo, int nstore,
    float* __restrict__ O32, const float* __restrict__ RES,
    _Float16* __restrict__ XM,
    int K, int nch, int amap, int emap, int epi, int shift)
{
  __shared__ _Float16 As[128][40];
  int tid  = threadIdx.x;
  int lane = tid & 63, wave = tid >> 6;
  int quad = lane >> 4, ln16 = lane & 15;
  int row0 = blockIdx.y * 128;
  int col0 = blockIdx.x * 64;

  f32x4 acc[2][4];
  #pragma unroll
  for (int mt = 0; mt < 2; ++mt)
    #pragma unroll
    for (int nb = 0; nb < 4; ++nb)
      #pragma unroll
      for (int r = 0; r < 4; ++r) acc[mt][nb][r] = 0.f;

  const _Float16* wlane = Wp + (size_t)lane*8;

  for (int c = 0; c < nch; ++c) {
    int k0 = c * 32;
    if (c) __syncthreads();
    // stage A: 128 rows x 4 segs = 512 tasks
    #pragma unroll
    for (int i = 0; i < 2; ++i) {
      int task = i*256 + tid;
      int ar = task >> 2, ak = (task & 3) * 8;
      int gr = row0 + ar;
      int sr = amap ? ocab_src_row(gr) : gr;
      h8 av;
      #pragma unroll
      for (int j = 0; j < 8; ++j) av[j] = (_Float16)0.f;
      if (sr >= 0) {
        const _Float16* ap = A + (size_t)sr*lda + k0 + ak;
        if (k0 + ak + 8 <= K) av = *(const h8*)ap;
        else {
          #pragma unroll
          for (int j = 0; j < 8; ++j)
            if (k0 + ak + j < K) av[j] = ap[j];
        }
      }
      *(h8*)&As[ar][ak] = av;
    }
    // B frags direct from global (packed, lane-contiguous)
    h8 bf[4];
    #pragma unroll
    for (int nb = 0; nb < 4; ++nb)
      bf[nb] = *(const h8*)(wlane + (size_t)(blockIdx.x*nch + c)*PKG + (size_t)nb*512);
    __syncthreads();
    h8 af0 = *(const h8*)&As[wave*32 + ln16][quad*8];
    h8 af1 = *(const h8*)&As[wave*32 + 16 + ln16][quad*8];
    #pragma unroll
    for (int nb = 0; nb < 4; ++nb) {
      acc[0][nb] = __builtin_amdgcn_mfma_f32_16x16x32_f16(af0, bf[nb], acc[0][nb], 0, 0, 0);
      acc[1][nb] = __builtin_amdgcn_mfma_f32_16x16x32_f16(af1, bf[nb], acc[1][nb], 0, 0, 0);
    }
  }

  #pragma unroll
  for (int mt = 0; mt < 2; ++mt)
    #pragma unroll
    for (int r = 0; r < 4; ++r) {
      int m = row0 + wave*32 + mt*16 + quad*4 + r;
      int dst = emap ? win_to_nat(m, shift) : m;
      #pragma unroll
      for (int nb = 0; nb < 4; ++nb) {
        int n = col0 + nb*16 + ln16;
        if (n < nstore) {
          float v = acc[mt][nb][r] + bias[n];
          if (epi == 2) {
            v += RES[(size_t)dst*180 + n];
            O32[(size_t)dst*180 + n] = v;
            XM[(size_t)dst*192 + n] = (_Float16)v;
          } else {
            if (epi == 1) v = gelu_exact(v);
            O16[(size_t)dst*ldo + n] = (_Float16)v;
          }
        }
      }
    }
}

// ---------------------------------------------------------------------------
// MFMA f16 3x3 conv, 2-row tiles (2 image rows x 64 px x 64 oc per block).
// f16 input only (padded strides -> unguarded h8 loads). Halo 4x66 in LDS.
// O16: f16 stride 64 zero-padded; else O32 = acc+bias+RES (+ XM mirror).
// grid = (ceil(OC/64), 288), 256 threads.
// ---------------------------------------------------------------------------
__global__ __launch_bounds__(256) void conv9_mfma(
    const _Float16* __restrict__ Xh, int ldah,
    const _Float16* __restrict__ Wp, const float* __restrict__ bias,
    const float* __restrict__ scale, const float* __restrict__ RES,
    float* __restrict__ O32, _Float16* __restrict__ XM,
    _Float16* __restrict__ O16, int OC, int nch)
{
  __shared__ _Float16 hs[4][66][40];
  int tid  = threadIdx.x;
  int lane = tid & 63, wave = tid >> 6;
  int quad = lane >> 4, ln16 = lane & 15;
  int by = blockIdx.y;
  int rp = by / 3, wb = by - rp*3;
  int h0 = rp*2;
  int w0 = wb*64;
  int col0 = blockIdx.x * 64;

  f32x4 acc[2][4];
  #pragma unroll
  for (int mt = 0; mt < 2; ++mt)
    #pragma unroll
    for (int nb = 0; nb < 4; ++nb)
      #pragma unroll
      for (int r = 0; r < 4; ++r) acc[mt][nb][r] = 0.f;

  for (int c = 0; c < nch; ++c) {
    int k0 = c * 32;
    if (c) __syncthreads();
    for (int idx = tid; idx < 4*66*4; idx += 256) {
      int r    = idx / 264;
      int rem  = idx - r*264;
      int px   = rem >> 2;
      int ks   = (rem & 3) * 8;
      int gh = h0 - 1 + r, gw = w0 - 1 + px;
      h8 hv;
      #pragma unroll
      for (int j = 0; j < 8; ++j) hv[j] = (_Float16)0.f;
      if ((unsigned)gh < (unsigned)HH && (unsigned)gw < (unsigned)WW) {
        hv = *(const h8*)(Xh + (size_t)(gh*WW + gw) * ldah + k0 + ks);
        if (scale) {
          #pragma unroll
          for (int j = 0; j < 8; ++j)
            hv[j] = (_Float16)((float)hv[j] * scale[k0 + ks + j]);
        }
      }
      *(h8*)&hs[r][px][ks] = hv;
    }
    __syncthreads();

    const _Float16* wpc = Wp + (size_t)(blockIdx.x*nch + c) * PKC + (size_t)lane*8;
    h8 bf[4];
    #pragma unroll
    for (int nb = 0; nb < 4; ++nb)
      bf[nb] = *(const h8*)(wpc + (size_t)nb*512);
    #pragma unroll
    for (int tap = 0; tap < 9; ++tap) {
      h8 bfn[4];
      if (tap < 8) {
        #pragma unroll
        for (int nb = 0; nb < 4; ++nb)
          bfn[nb] = *(const h8*)(wpc + (size_t)(tap+1)*2048 + (size_t)nb*512);
      }
      int dyy = tap / 3, dxt = tap - dyy*3;
      h8 af0 = *(const h8*)&hs[dyy][wave*16 + ln16 + dxt][quad*8];
      h8 af1 = *(const h8*)&hs[dyy + 1][wave*16 + ln16 + dxt][quad*8];
      #pragma unroll
      for (int nb = 0; nb < 4; ++nb) {
        acc[0][nb] = __builtin_amdgcn_mfma_f32_16x16x32_f16(af0, bf[nb], acc[0][nb], 0, 0, 0);
        acc[1][nb] = __builtin_amdgcn_mfma_f32_16x16x32_f16(af1, bf[nb], acc[1][nb], 0, 0, 0);
      }
      if (tap < 8) {
        #pragma unroll
        for (int nb = 0; nb < 4; ++nb) bf[nb] = bfn[nb];
      }
    }
  }

  #pragma unroll
  for (int mt = 0; mt < 2; ++mt)
    #pragma unroll
    for (int r = 0; r < 4; ++r) {
      int p = (h0 + mt)*WW + w0 + wave*16 + quad*4 + r;
      #pragma unroll
      for (int nb = 0; nb < 4; ++nb) {
        int oc = col0 + nb*16 + ln16;
        if (O16) {
          float v = (oc < OC) ? acc[mt][nb][r] + bias[oc] : 0.f;
          O16[(size_t)p*64 + oc] = (_Float16)v;
        } else if (oc < OC) {
          float v = acc[mt][nb][r] + bias[oc] + RES[(size_t)p * OC + oc];
          O32[(size_t)p * OC + oc] = v;
          if (XM) XM[(size_t)p*192 + oc] = (_Float16)v;
        }
      }
    }
}

// ---------------------------------------------------------------------------
// MFMA window attention, f16 QKV (stride 576, heads padded to 32).
// ---------------------------------------------------------------------------
__global__ __launch_bounds__(256) void win_attn_mfma(
    const _Float16* __restrict__ QKV, const float* __restrict__ relb,
    _Float16* __restrict__ OUT, int shift)
{
  __shared__ _Float16 Kf[256][40];
  __shared__ _Float16 Vt[32][264];
  __shared__ _Float16 rbs[962];
  __shared__ unsigned char rg[256];
  int b = blockIdx.x;
  int w = b / HEADS, hd = b - (b / HEADS)*HEADS;
  int tid = threadIdx.x, lane = tid & 63, wave = tid >> 6;
  int quad = lane >> 4, ln16 = lane & 15;
  const _Float16* base = QKV + (size_t)(w*NTW)*576;

  #pragma unroll
  for (int i = 0; i < 4; ++i) {
    int task = i*256 + tid;
    int row = task >> 2, seg = (task & 3) * 8;
    *(h8*)&Kf[row][seg] = *(const h8*)(base + (size_t)row*576 + 192 + hd*32 + seg);
    h8 hv = *(const h8*)(base + (size_t)row*576 + 384 + hd*32 + seg);
    #pragma unroll
    for (int j = 0; j < 8; ++j) Vt[seg + j][row] = hv[j];
  }
  for (int i = tid; i < 961; i += 256) rbs[i] = (_Float16)relb[i*HEADS + hd];
  if (shift > 0) {
    int wh = w / NWW, ww = w - wh*NWW;
    int rh = wh*WS + (tid >> 4), rw = ww*WS + (tid & 15);
    int regh = (rh < HH - WS) ? 0 : (rh < HH - 8 ? 1 : 2);
    int regw = (rw < WW - WS) ? 0 : (rw < WW - 8 ? 1 : 2);
    rg[tid] = (unsigned char)(regh*3 + regw);
  }

  h8 bq[4];
  #pragma unroll
  for (int qi = 0; qi < 4; ++qi) {
    int q = wave*64 + qi*16 + ln16;
    bq[qi] = *(const h8*)(base + (size_t)q*576 + hd*32 + quad*8);
  }
  __syncthreads();

  float mrun[4], lrun[4];
  f32x4 accO[4][2];
  #pragma unroll
  for (int qi = 0; qi < 4; ++qi) {
    mrun[qi] = -1e30f; lrun[qi] = 0.f;
    #pragma unroll
    for (int r = 0; r < 4; ++r) { accO[qi][0][r] = 0.f; accO[qi][1][r] = 0.f; }
  }
  int rgq[4] = {0,0,0,0};
  if (shift > 0) {
    #pragma unroll
    for (int qi = 0; qi < 4; ++qi) rgq[qi] = rg[wave*64 + qi*16 + ln16];
  }
  const f32x4 zero4 = {0.f,0.f,0.f,0.f};

  for (int kb = 0; kb < 4; ++kb) {
    f32x4 st[4][4];
    #pragma unroll
    for (int kt = 0; kt < 4; ++kt) {
      h8 ak = *(const h8*)&Kf[kb*64 + kt*16 + ln16][quad*8];
      #pragma unroll
      for (int qi = 0; qi < 4; ++qi)
        st[kt][qi] = __builtin_amdgcn_mfma_f32_16x16x32_f16(ak, bq[qi], zero4, 0, 0, 0);
    }
    #pragma unroll
    for (int qi = 0; qi < 4; ++qi) {
      int q = wave*64 + qi*16 + ln16;
      int qrr = q >> 4, qcc = q & 15;
      float bmax = -1e30f;
      #pragma unroll
      for (int kt = 0; kt < 4; ++kt) {
        int bidx0 = (qrr - (kb*4 + kt) + 15)*31 + qcc + 15 - quad*4;
        #pragma unroll
        for (int r = 0; r < 4; ++r) {
          float s = st[kt][qi][r] + (float)rbs[bidx0 - r];
          if (shift > 0) {
            int key = kb*64 + kt*16 + quad*4 + r;
            if (rg[key] != rgq[qi]) s -= 100.f;
          }
          st[kt][qi][r] = s;
          bmax = fmaxf(bmax, s);
        }
      }
      bmax = fmaxf(bmax, __shfl_xor(bmax, 16));
      bmax = fmaxf(bmax, __shfl_xor(bmax, 32));
      float mnew  = fmaxf(mrun[qi], bmax);
      float alpha = __expf(mrun[qi] - mnew);
      mrun[qi] = mnew;
      float ps = 0.f;
      #pragma unroll
      for (int kt = 0; kt < 4; ++kt)
        #pragma unroll
        for (int r = 0; r < 4; ++r) {
          float p = __expf(st[kt][qi][r] - mnew);
          st[kt][qi][r] = p; ps += p;
        }
      ps += __shfl_xor(ps, 16);
      ps += __shfl_xor(ps, 32);
      lrun[qi] = lrun[qi]*alpha + ps;
      #pragma unroll
      for (int r = 0; r < 4; ++r) {
        float fr = __shfl(alpha, quad*4 + r);
        accO[qi][0][r] *= fr;
        accO[qi][1][r] *= fr;
      }
    }
    #pragma unroll
    for (int kt = 0; kt < 4; ++kt) {
      int kbase = kb*64 + kt*16 + quad*4;
      h4 bv0 = *(const h4*)&Vt[ln16][kbase];
      h4 bv1 = *(const h4*)&Vt[16 + ln16][kbase];
      #pragma unroll
      for (int qi = 0; qi < 4; ++qi) {
        h4 ap;
        #pragma unroll
        for (int j = 0; j < 4; ++j) ap[j] = (_Float16)st[kt][qi][j];
        accO[qi][0] = __builtin_amdgcn_mfma_f32_16x16x16f16(ap, bv0, accO[qi][0], 0, 0, 0);
        accO[qi][1] = __builtin_amdgcn_mfma_f32_16x16x16f16(ap, bv1, accO[qi][1], 0, 0, 0);
      }
    }
  }

  #pragma unroll
  for (int qi = 0; qi < 4; ++qi) {
    float linv = 1.f / lrun[qi];
    #pragma unroll
    for (int r = 0; r < 4; ++r) {
      float fr = __shfl(linv, quad*4 + r);
      int q = wave*64 + qi*16 + quad*4 + r;
      _Float16* o = OUT + (size_t)(w*NTW + q)*192 + hd*HD;
      o[ln16] = (_Float16)(accO[qi][0][r] * fr);
      if (ln16 < HD - 16) o[16 + ln16] = (_Float16)(accO[qi][1][r] * fr);
    }
  }
}

// ---------------------------------------------------------------------------
// MFMA OCAB attention, f16 Q (stride 192, pre-scaled) + f16 KV (stride 384).
// ---------------------------------------------------------------------------
__global__ __launch_bounds__(256) void ocab_attn_mfma(
    const _Float16* __restrict__ Q, const _Float16* __restrict__ KV,
    _Float16* __restrict__ OUT)
{
  constexpr int CH = 192;
  __shared__ _Float16 Kf[CH][40];
  __shared__ _Float16 Vt[32][200];
  int b = blockIdx.x;
  int w = b / HEADS, hd = b - (b / HEADS)*HEADS;
  int tid = threadIdx.x, lane = tid & 63, wave = tid >> 6;
  int quad = lane >> 4, ln16 = lane & 15;

  h8 bq[4];
  #pragma unroll
  for (int qi = 0; qi < 4; ++qi) {
    int q = wave*64 + qi*16 + ln16;
    bq[qi] = *(const h8*)(Q + (size_t)(w*NTW + q)*192 + hd*32 + quad*8);
  }

  float mrun[4], lrun[4];
  f32x4 accO[4][2];
  #pragma unroll
  for (int qi = 0; qi < 4; ++qi) {
    mrun[qi] = -1e30f; lrun[qi] = 0.f;
    #pragma unroll
    for (int r = 0; r < 4; ++r) { accO[qi][0][r] = 0.f; accO[qi][1][r] = 0.f; }
  }
  const f32x4 zero4 = {0.f,0.f,0.f,0.f};

  for (int ch = 0; ch < 3; ++ch) {
    __syncthreads();
    #pragma unroll
    for (int i = 0; i < 3; ++i) {
      int task = i*256 + tid;
      int row = task >> 2, seg = (task & 3) * 8;
      const _Float16* kvr = KV + (size_t)(w*NKV + ch*CH + row)*384;
      *(h8*)&Kf[row][seg] = *(const h8*)(kvr + hd*32 + seg);
      h8 hv = *(const h8*)(kvr + 192 + hd*32 + seg);
      #pragma unroll
      for (int j = 0; j < 8; ++j) Vt[seg + j][row] = hv[j];
    }
    __syncthreads();

    for (int kb = 0; kb < 3; ++kb) {
      f32x4 st[4][4];
      #pragma unroll
      for (int kt = 0; kt < 4; ++kt) {
        h8 ak = *(const h8*)&Kf[kb*64 + kt*16 + ln16][quad*8];
        #pragma unroll
        for (int qi = 0; qi < 4; ++qi)
          st[kt][qi] = __builtin_amdgcn_mfma_f32_16x16x32_f16(ak, bq[qi], zero4, 0, 0, 0);
      }
      #pragma unroll
      for (int qi = 0; qi < 4; ++qi) {
        float bmax = -1e30f;
        #pragma unroll
        for (int kt = 0; kt < 4; ++kt)
          #pragma unroll
          for (int r = 0; r < 4; ++r) bmax = fmaxf(bmax, st[kt][qi][r]);
        bmax = fmaxf(bmax, __shfl_xor(bmax, 16));
        bmax = fmaxf(bmax, __shfl_xor(bmax, 32));
        float mnew  = fmaxf(mrun[qi], bmax);
        float alpha = __expf(mrun[qi] - mnew);
        mrun[qi] = mnew;
        float ps = 0.f;
        #pragma unroll
        for (int kt = 0; kt < 4; ++kt)
          #pragma unroll
          for (int r = 0; r < 4; ++r) {
            float p = __expf(st[kt][qi][r] - mnew);
            st[kt][qi][r] = p; ps += p;
          }
        ps += __shfl_xor(ps, 16);
        ps += __shfl_xor(ps, 32);
        lrun[qi] = lrun[qi]*alpha + ps;
        #pragma unroll
        for (int r = 0; r < 4; ++r) {
          float fr = __shfl(alpha, quad*4 + r);
          accO[qi][0][r] *= fr;
          accO[qi][1][r] *= fr;
        }
      }
      #pragma unroll
      for (int kt = 0; kt < 4; ++kt) {
        int kbase = kb*64 + kt*16 + quad*4;
        h4 bv0 = *(const h4*)&Vt[ln16][kbase];
        h4 bv1 = *(const h4*)&Vt[16 + ln16][kbase];
        #pragma unroll
        for (int qi = 0; qi < 4; ++qi) {
          h4 ap;
          #pragma unroll
          for (int j = 0; j < 4; ++j) ap[j] = (_Float16)st[kt][qi][j];
          accO[qi][0] = __builtin_amdgcn_mfma_f32_16x16x16f16(ap, bv0, accO[qi][0], 0, 0, 0);
          accO[qi][1] = __builtin_amdgcn_mfma_f32_16x16x16f16(ap, bv1, accO[qi][1], 0, 0, 0);
        }
      }
    }
  }

  #pragma unroll
  for (int qi = 0; qi < 4; ++qi) {
    float linv = 1.f / lrun[qi];
    #pragma unroll
    for (int r = 0; r < 4; ++r) {
      float fr = __shfl(linv, quad*4 + r);
      int q = wave*64 + qi*16 + quad*4 + r;
      _Float16* o = OUT + (size_t)(w*NTW + q)*192 + hd*HD;
      o[ln16] = (_Float16)(accO[qi][0][r] * fr);
      if (ln16 < HD - 16) o[16 + ln16] = (_Float16)(accO[qi][1][r] * fr);
    }
  }
}

// ---------------------------------------------------------------------------
__global__ __launch_bounds__(256) void colsum_kernel(
    const _Float16* __restrict__ COMP, float* __restrict__ S)
{
  int tid = threadIdx.x;
  int seg = tid & 7, rb = tid >> 3;
  int row0 = blockIdx.x * 128;
  float a[8] = {};
  #pragma unroll
  for (int i = 0; i < 4; ++i) {
    int row = row0 + i*32 + rb;
    h8 v = *(const h8*)(COMP + (size_t)row*64 + seg*8);
    #pragma unroll
    for (int j = 0; j < 8; ++j) a[j] += (float)v[j];
  }
  __shared__ float sA[64];
  if (tid < 64) sA[tid] = 0.f;
  __syncthreads();
  #pragma unroll
  for (int j = 0; j < 8; ++j) atomicAdd(&sA[seg*8 + j], a[j]);
  __syncthreads();
  if (tid < 60) atomicAdd(&S[tid], sA[tid]);
}

__global__ __launch_bounds__(64) void se_kernel(
    const float* __restrict__ S, const float* __restrict__ w1,
    const float* __restrict__ b1, const float* __restrict__ w2,
    const float* __restrict__ b2, float* __restrict__ G)
{
  __shared__ float hid[CSE];
  int t = threadIdx.x;
  if (t < CSE) {
    float a = b1[t];
    for (int c = 0; c < CCH; ++c) a += (S[c] * (1.f/NT)) * w1[c * CSE + t];
    hid[t] = fmaxf(a, 0.f);
  }
  __syncthreads();
  if (t < CCH) {
    float a = b2[t];
    #pragma unroll
    for (int j = 0; j < CSE; ++j) a += hid[j] * w2[j * CCH + t];
    G[t] = 1.f / (1.f + __expf(-a));
  }
}

// ---------------------------------------------------------------------------

extern "C" void kernel_launch(void* const* d_in, const int* in_sizes, int n_in,
                              void* d_out, int out_size, void* d_ws, size_t ws_size,
                              hipStream_t stream) {
  const float* x_in   = (const float*)d_in[0];
  const float* n1w    = (const float*)d_in[1];
  const float* n1b    = (const float*)d_in[2];
  const float* qkvw   = (const float*)d_in[3];
  const float* qkvb   = (const float*)d_in[4];
  const float* relb   = (const float*)d_in[5];
  const float* projw  = (const float*)d_in[6];
  const float* projb  = (const float*)d_in[7];
  const float* ccw    = (const float*)d_in[8];
  const float* ccb    = (const float*)d_in[9];
  const float* ca1w   = (const float*)d_in[10];
  const float* ca1b   = (const float*)d_in[11];
  const float* ca2w   = (const float*)d_in[12];
  const float* ca2b   = (const float*)d_in[13];
  const float* cew    = (const float*)d_in[14];
  const float* ceb    = (const float*)d_in[15];
  const float* n2w    = (const float*)d_in[16];
  const float* n2b    = (const float*)d_in[17];
  const float* m1w    = (const float*)d_in[18];
  const float* m1b    = (const float*)d_in[19];
  const float* m2w    = (const float*)d_in[20];
  const float* m2b    = (const float*)d_in[21];
  const float* onw    = (const float*)d_in[22];
  const float* onb    = (const float*)d_in[23];
  const float* oqw    = (const float*)d_in[24];
  const float* oqb    = (const float*)d_in[25];
  const float* okvw   = (const float*)d_in[26];
  const float* okvb   = (const float*)d_in[27];
  const float* opw    = (const float*)d_in[28];
  const float* opb    = (const float*)d_in[29];
  const float* convw  = (const float*)d_in[30];
  const float* convb  = (const float*)d_in[31];

  float* ws   = (float*)d_ws;
  float*     X    = ws + OFF_X;
  _Float16*  A    = (_Float16*)(ws + OFF_A);
  _Float16*  Bq   = (_Float16*)(ws + OFF_B);
  _Float16*  COMP = (_Float16*)(ws + OFF_COMP);
  float*     S    = ws + OFF_S;
  float*     G    = ws + OFF_G;
  _Float16*  QKV  = (_Float16*)(ws + OFF_QKV);
  _Float16*  PK   = (_Float16*)(ws + OFF_PK);
  float*     PB   = ws + OFF_PB;
  _Float16*  X16  = (_Float16*)(ws + OFF_X16);

  float* qkvB = PB;
  float* oqB  = PB + 6*576;
  float* okvB = oqB + 192;

  const float scl = 0.18257418583505536f;

  initx_kernel<<<NT/4, 256, 0, stream>>>(x_in, X, X16);

  #define GRID(n) dim3(((n)+255)/256)
  pack_gemmw<<<GRID(6*QKV_PL), 256, 0, stream>>>(qkvw, PK+PO_QKV, 180, 540, 6, 1, 1.f, QKV_PL, 6, 180*540);
  pack_gemmw<<<GRID(6*PROJ_PL),256, 0, stream>>>(projw, PK+PO_PROJ,180, 180, 6, 0, 1.f, PROJ_PL,6, 180*180);
  pack_gemmw<<<GRID(6*M1_PL), 256, 0, stream>>>(m1w,  PK+PO_M1,  180, 360, 6, 0, 1.f, M1_PL,  6, 180*360);
  pack_gemmw<<<GRID(6*M2_PL), 256, 0, stream>>>(m2w,  PK+PO_M2,  360, 180,12, 0, 1.f, M2_PL,  6, 360*180);
  pack_gemmw<<<GRID(OQ_PL),   256, 0, stream>>>(oqw,  PK+PO_OQ,  180, 180, 6, 3, scl, OQ_PL,  1, 0);
  pack_gemmw<<<GRID(OKV_PL),  256, 0, stream>>>(okvw, PK+PO_OKV, 180, 360, 6, 2, 1.f, OKV_PL, 1, 0);
  pack_gemmw<<<GRID(OP_PL),   256, 0, stream>>>(opw,  PK+PO_OP,  180, 180, 6, 0, 1.f, OP_PL,  1, 0);
  pack_convw<<<GRID(6*CC_PL), 256, 0, stream>>>(ccw,  PK+PO_CC,  180,  60, 6, CC_PL, 6, 60*180*9);
  pack_convw<<<GRID(6*CE_PL), 256, 0, stream>>>(cew,  PK+PO_CE,   60, 180, 2, CE_PL, 6, 180*60*9);
  pack_convw<<<GRID(FIN_PL),  256, 0, stream>>>(convw,PK+PO_FIN, 180, 180, 6, FIN_PL,1, 0);
  pack_bias<<<GRID(6*576), 256, 0, stream>>>(qkvb, qkvB, 540, 576, 1, 1.f, 6);
  pack_bias<<<GRID(192),   256, 0, stream>>>(oqb,  oqB,  180, 192, 3, scl, 1);
  pack_bias<<<GRID(384),   256, 0, stream>>>(okvb, okvB, 360, 384, 2, 1.f, 1);

  const int MB128 = NT / 128;   // 288
  const int CB    = 288;        // conv 2-row blocks

  for (int i = 0; i < DEPTH; ++i) {
    int shift = (i % 2 == 0) ? 0 : WS / 2;
    ln2_kernel<<<NT/4, 256, 0, stream>>>(X16, n1w + i*C, n1b + i*C, A, 1, shift);
    gemm2<<<dim3(9, MB128), 256, 0, stream>>>(
        A, 192, PK+PO_QKV + (size_t)i*QKV_PL, qkvB + i*576,
        QKV, 576, 576, nullptr, nullptr, nullptr, 180, 6, 0, 0, 0, 0);
    win_attn_mfma<<<NWIN*HEADS, 256, 0, stream>>>(
        QKV, relb + (size_t)i*961*HEADS, A, shift);
    gemm2<<<dim3(3, MB128), 256, 0, stream>>>(
        A, 192, PK+PO_PROJ + (size_t)i*PROJ_PL, projb + i*C,
        nullptr, 0, 180, X, X, X16, 180, 6, 0, 1, 2, shift);
    conv9_mfma<<<dim3(1, CB), 256, 0, stream>>>(
        X16, 192, PK+PO_CC + (size_t)i*CC_PL, ccb + i*CCH,
        nullptr, nullptr, nullptr, nullptr, COMP, 60, 6);
    (void)hipMemsetAsync(S, 0, 64*sizeof(float), stream);
    colsum_kernel<<<288, 256, 0, stream>>>(COMP, S);
    se_kernel<<<1, 64, 0, stream>>>(
        S, ca1w + (size_t)i*CCH*CSE, ca1b + (size_t)i*CSE,
        ca2w + (size_t)i*CSE*CCH, ca2b + (size_t)i*CCH, G);
    conv9_mfma<<<dim3(3, CB), 256, 0, stream>>>(
        COMP, 64, PK+PO_CE + (size_t)i*CE_PL, ceb + i*C,
        G, X, X, X16, nullptr, 180, 2);
    ln2_kernel<<<NT/4, 256, 0, stream>>>(X16, n2w + i*C, n2b + i*C, A, 0, 0);
    gemm2<<<dim3(6, MB128), 256, 0, stream>>>(
        A, 192, PK+PO_M1 + (size_t)i*M1_PL, m1b + i*HID,
        QKV, 384, 360, nullptr, nullptr, nullptr, 180, 6, 0, 0, 1, 0);
    gemm2<<<dim3(3, MB128), 256, 0, stream>>>(
        QKV, 384, PK+PO_M2 + (size_t)i*M2_PL, m2b + i*C,
        nullptr, 0, 180, X, X, X16, 360, 12, 0, 0, 2, 0);
  }

  // ---- OCAB ----
  ln2_kernel<<<NT/4, 256, 0, stream>>>(X16, onw, onb, A, 1, 0);
  gemm2<<<dim3(3, MB128), 256, 0, stream>>>(
      A, 192, PK+PO_OQ, oqB, Bq, 192, 192, nullptr, nullptr, nullptr, 180, 6, 0, 0, 0, 0);
  gemm2<<<dim3(6, NWIN*NKV/128), 256, 0, stream>>>(
      A, 192, PK+PO_OKV, okvB, QKV, 384, 384, nullptr, nullptr, nullptr, 180, 6, 1, 0, 0, 0);
  ocab_attn_mfma<<<NWIN*HEADS, 256, 0, stream>>>(Bq, QKV, A);
  gemm2<<<dim3(3, MB128), 256, 0, stream>>>(
      A, 192, PK+PO_OP, opb, nullptr, 0, 180, X, X, X16, 180, 6, 0, 1, 2, 0);

  // ---- final conv + global shortcut -> d_out ----
  conv9_mfma<<<dim3(3, CB), 256, 0, stream>>>(
      X16, 192, PK+PO_FIN, convb, nullptr, x_in,
      (float*)d_out, nullptr, nullptr, 180, 6);
}